// Round 4
// baseline (367.278 us; speedup 1.0000x reference)
//
#include <hip/hip_runtime.h>
#include <hip/hip_bf16.h>
#include <math.h>

#define Tn   8192
#define Hn   1024
#define En   8
#define DFFn 4096

typedef __attribute__((ext_vector_type(8))) short bf16x8;  // 8 bf16 = 4 VGPRs
typedef __attribute__((ext_vector_type(4))) float f32x4;

static __device__ inline unsigned short f2bf(float f) {
    __hip_bfloat16 h = __float2bfloat16(f);
    return __builtin_bit_cast(unsigned short, h);
}

// ---------------- gate + x->bf16 conversion + fused finalize ----------------
// 512 blocks x 256 threads; one wave per token, stride 2048 (4 toks/wave).
// Last block (atomic ticket) computes aux_loss + counts into out_tail.
__global__ __launch_bounds__(256) void gate_convert(
    const float* __restrict__ x, const float* __restrict__ gW,
    const float* __restrict__ gb, unsigned short* __restrict__ xbf,
    float* __restrict__ tokw, float* __restrict__ load_sum,
    int* __restrict__ counts, int* __restrict__ ctr,
    float* __restrict__ out_tail)
{
    __shared__ float s_load[En];
    __shared__ int   s_cnt[En];
    __shared__ int   s_ticket;
    const int tid = threadIdx.x;
    if (tid < En) { s_load[tid] = 0.f; s_cnt[tid] = 0; }
    __syncthreads();

    const int lane = tid & 63;
    const int wv   = tid >> 6;

    for (int tok = blockIdx.x * 4 + wv; tok < Tn; tok += 2048) {
        const float4* xr = (const float4*)(x + (size_t)tok * Hn);
        float acc[8] = {0.f,0.f,0.f,0.f,0.f,0.f,0.f,0.f};
        #pragma unroll
        for (int j = 0; j < Hn / 256; ++j) {           // 4 iterations
            int h4 = j * 64 + lane;
            float4 xv = xr[h4];
            ushort4 pk;
            pk.x = f2bf(xv.x); pk.y = f2bf(xv.y);
            pk.z = f2bf(xv.z); pk.w = f2bf(xv.w);
            ((ushort4*)xbf)[(size_t)tok * (Hn / 4) + h4] = pk;
            const float* wr = gW + (size_t)h4 * 4 * En;   // 4 rows of gW
            float xs[4] = {xv.x, xv.y, xv.z, xv.w};
            #pragma unroll
            for (int c = 0; c < 4; ++c)
                #pragma unroll
                for (int e = 0; e < 8; ++e)
                    acc[e] += xs[c] * wr[c * 8 + e];
        }
        #pragma unroll
        for (int e = 0; e < 8; ++e) {
            float v = acc[e];
            #pragma unroll
            for (int off = 32; off > 0; off >>= 1) v += __shfl_xor(v, off, 64);
            acc[e] = v + gb[e];
        }
        if (lane == 0) {
            #pragma unroll
            for (int e = 0; e < 8; ++e) atomicAdd(&s_load[e], acc[e]);
            int i1 = 0; float v1 = acc[0];
            #pragma unroll
            for (int e = 1; e < 8; ++e) if (acc[e] > v1) { v1 = acc[e]; i1 = e; }
            int i2 = -1; float v2 = -3.0e38f;
            #pragma unroll
            for (int e = 0; e < 8; ++e) if (e != i1 && acc[e] > v2) { v2 = acc[e]; i2 = e; }
            atomicAdd(&s_cnt[i1], 1);
            atomicAdd(&s_cnt[i2], 1);
            float e2 = __expf(v2 - v1);
            float t  = 1.0f + e2;
            tokw[tok] = 1.0f / t + e2 / t;   // softmax(top2).sum()
        }
    }
    __syncthreads();
    if (tid < En) {
        atomicAdd(&load_sum[tid], s_load[tid]);
        atomicAdd(&counts[tid],   s_cnt[tid]);
    }
    // ticket: last block to arrive finalizes (device-scope fence + atomics)
    __threadfence();
    if (tid == 0) s_ticket = atomicAdd(ctr, 1);
    __syncthreads();
    if (s_ticket == (int)gridDim.x - 1 && tid == 0) {
        __threadfence();
        float aux = 0.f;
        #pragma unroll
        for (int e = 0; e < En; ++e) {
            float m = load_sum[e] * (1.0f / (float)Tn);
            aux += m * m;
        }
        out_tail[0] = aux;
        #pragma unroll
        for (int e = 0; e < En; ++e) out_tail[1 + e] = (float)counts[e];
    }
}

// ------------- both W transposes in one launch: [K][N] fp32 -> [N][K] bf16 --
__global__ __launch_bounds__(256) void transpose_both(
    const float* __restrict__ W1, const float* __restrict__ W2,
    __hip_bfloat16* __restrict__ W1t, __hip_bfloat16* __restrict__ W2t)
{
    __shared__ float tile[32][33];
    int id = blockIdx.x;
    const float* src; __hip_bfloat16* dst; int Kd, Nd, bx, by;
    if (id < 4096) { src = W1; dst = W1t; Kd = Hn;   Nd = DFFn;
                     bx = id & 127; by = id >> 7; }
    else { id -= 4096; src = W2; dst = W2t; Kd = DFFn; Nd = Hn;
           bx = id & 31;  by = id >> 5; }
    const int n0 = bx * 32, k0 = by * 32;
    const int tx = threadIdx.x & 31, ty = threadIdx.x >> 5;  // ty: 0..7
    #pragma unroll
    for (int r = 0; r < 32; r += 8)
        tile[ty + r][tx] = src[(size_t)(k0 + ty + r) * Nd + n0 + tx];
    __syncthreads();
    #pragma unroll
    for (int r = 0; r < 32; r += 8)
        dst[(size_t)(n0 + ty + r) * Kd + k0 + tx] = __float2bfloat16(tile[tx][ty + r]);
}

// ---------------- m97-style bf16 GEMM, C = epilogue(A @ Bt^T + bias) ------
// A : [M][K] bf16 row-major ; Bt : [N][K] bf16 row-major.
// 1D grid, XCD-aware swizzle (id%8 = xcd, x fastest within an XCD).
// LDS k-chunk rotation kills the 8-way bank conflict on fragment reads:
//   slot s of row R holds global chunk (s - (R>>1))&3; reader of chunk q
//   uses slot (q + (fr>>1))&3. Rows +64 rotate identically (64>>1 % 4 == 0).
// EPI==0: C = bf16( gelu_tanh(v + bias) )    (hdd)
// EPI==1: C = fp32( (v + bias) * tokw[row] ) (final output)
template<int EPI>
__global__ __launch_bounds__(256) void gemm_bt(
    const __hip_bfloat16* __restrict__ A,
    const __hip_bfloat16* __restrict__ Bt,
    const float* __restrict__ bias,
    const float* __restrict__ tokw,
    void* __restrict__ C, int N, int K, int nxlog2)
{
    __shared__ __hip_bfloat16 sA[128 * 32];   // no padding: global_load_lds layout
    __shared__ __hip_bfloat16 sB[128 * 32];

    const int tid  = threadIdx.x;
    const int lane = tid & 63;
    const int wv   = tid >> 6;
    const int wm   = (wv >> 1) * 64;
    const int wn   = (wv & 1) * 64;

    // XCD swizzle
    const int id     = blockIdx.x;
    const int xcd    = id & 7;
    const int slot   = id >> 3;
    const int bx     = slot & ((1 << nxlog2) - 1);
    const int ylocal = slot >> nxlog2;
    const int y_per  = (int)((gridDim.x >> 3) >> nxlog2);   // ny/8
    const int by     = xcd * y_per + ylocal;

    const int m0 = by * 128, n0 = bx * 128;

    f32x4 acc[4][4];
    const f32x4 zero = {0.f, 0.f, 0.f, 0.f};
    #pragma unroll
    for (int i = 0; i < 4; ++i)
        #pragma unroll
        for (int j = 0; j < 4; ++j) acc[i][j] = zero;

    // staging: thread t = (row r0 = t>>2, slot s = t&3) fetches global chunk
    // (s - (r0>>1))&3 of that row -> LDS addr t*16B (lane-contiguous).
    const int r0 = tid >> 2;
    const int kc = (((tid & 3) - (r0 >> 1)) & 3) * 8;
    const __hip_bfloat16* gA = A  + (size_t)(m0 + r0) * K + kc;
    const __hip_bfloat16* gB = Bt + (size_t)(n0 + r0) * K + kc;
    const size_t half = (size_t)64 * K;

    const int fr = lane & 15;
    const int fs = (((lane >> 4) + (fr >> 1)) & 3) * 8;   // rotated LDS slot

    for (int k0 = 0; k0 < K; k0 += 32) {
        __syncthreads();
        __builtin_amdgcn_global_load_lds(
            (const __attribute__((address_space(1))) void*)(gA + k0),
            (__attribute__((address_space(3))) void*)(sA + tid * 8), 16, 0, 0);
        __builtin_amdgcn_global_load_lds(
            (const __attribute__((address_space(1))) void*)(gA + half + k0),
            (__attribute__((address_space(3))) void*)(sA + 2048 + tid * 8), 16, 0, 0);
        __builtin_amdgcn_global_load_lds(
            (const __attribute__((address_space(1))) void*)(gB + k0),
            (__attribute__((address_space(3))) void*)(sB + tid * 8), 16, 0, 0);
        __builtin_amdgcn_global_load_lds(
            (const __attribute__((address_space(1))) void*)(gB + half + k0),
            (__attribute__((address_space(3))) void*)(sB + 2048 + tid * 8), 16, 0, 0);
        __syncthreads();

        bf16x8 af[4], bfr[4];
        #pragma unroll
        for (int mi = 0; mi < 4; ++mi)
            af[mi] = *(const bf16x8*)(sA + (wm + mi * 16 + fr) * 32 + fs);
        #pragma unroll
        for (int ni = 0; ni < 4; ++ni)
            bfr[ni] = *(const bf16x8*)(sB + (wn + ni * 16 + fr) * 32 + fs);
        #pragma unroll
        for (int mi = 0; mi < 4; ++mi)
            #pragma unroll
            for (int ni = 0; ni < 4; ++ni)
                acc[mi][ni] = __builtin_amdgcn_mfma_f32_16x16x32_bf16(
                    af[mi], bfr[ni], acc[mi][ni], 0, 0, 0);
    }

    // epilogue: C/D layout col = lane&15, row = (lane>>4)*4 + reg
    #pragma unroll
    for (int mi = 0; mi < 4; ++mi) {
        #pragma unroll
        for (int ni = 0; ni < 4; ++ni) {
            const int col   = n0 + wn + ni * 16 + (lane & 15);
            const int rbase = m0 + wm + mi * 16 + (lane >> 4) * 4;
            const float bv  = bias[col];
            #pragma unroll
            for (int i = 0; i < 4; ++i) {
                const int row = rbase + i;
                float v = acc[mi][ni][i] + bv;
                if (EPI == 0) {
                    // gelu tanh-form via sigmoid: gelu(v) ~= v * sigmoid(2u)
                    float u = 0.7978845608028654f * (v + 0.044715f * v * v * v);
                    float g = v / (1.0f + __expf(-2.0f * u));
                    ((__hip_bfloat16*)C)[(size_t)row * N + col] = __float2bfloat16(g);
                } else {
                    ((float*)C)[(size_t)row * N + col] = v * tokw[row];
                }
            }
        }
    }
}

extern "C" void kernel_launch(void* const* d_in, const int* in_sizes, int n_in,
                              void* d_out, int out_size, void* d_ws, size_t ws_size,
                              hipStream_t stream)
{
    const float* x  = (const float*)d_in[0];
    const float* gW = (const float*)d_in[1];
    const float* gb = (const float*)d_in[2];
    const float* W1 = (const float*)d_in[3];
    const float* b1 = (const float*)d_in[4];
    const float* W2 = (const float*)d_in[5];
    const float* b2 = (const float*)d_in[6];
    float* out = (float*)d_out;

    char* ws = (char*)d_ws;
    __hip_bfloat16* xbf = (__hip_bfloat16*)ws;  ws += (size_t)Tn * Hn * 2;     // 16 MB
    __hip_bfloat16* W1t = (__hip_bfloat16*)ws;  ws += (size_t)Hn * DFFn * 2;   //  8 MB
    __hip_bfloat16* W2t = (__hip_bfloat16*)ws;  ws += (size_t)Hn * DFFn * 2;   //  8 MB
    __hip_bfloat16* hdd = (__hip_bfloat16*)ws;  ws += (size_t)Tn * DFFn * 2;   // 64 MB
    float* tokw     = (float*)ws;               ws += (size_t)Tn * 4;          // 32 KB
    float* load_sum = (float*)ws;               ws += En * 4;
    int*   counts   = (int*)ws;                 ws += En * 4;
    int*   ctr      = (int*)ws;                 ws += 4;

    hipMemsetAsync(load_sum, 0, (En * 2 + 1) * 4, stream);  // load_sum+counts+ctr

    transpose_both<<<8192, 256, 0, stream>>>(W1, W2, W1t, W2t);
    gate_convert<<<512, 256, 0, stream>>>(x, gW, gb, (unsigned short*)xbf,
                                          tokw, load_sum, counts, ctr,
                                          out + (size_t)Tn * Hn);

    // hdd = gelu(x @ W1 + b1)            [8192 x 4096]; nx=32 -> nxlog2=5
    gemm_bt<0><<<(DFFn / 128) * (Tn / 128), 256, 0, stream>>>(
        xbf, W1t, b1, nullptr, hdd, DFFn, Hn, 5);
    // out = (hdd @ W2 + b2) * tokw[row]  [8192 x 1024]; nx=8 -> nxlog2=3
    gemm_bt<1><<<(Hn / 128) * (Tn / 128), 256, 0, stream>>>(
        hdd, W2t, b2, tokw, out, Hn, DFFn, 3);
}

// Round 5
// 324.218 us; speedup vs baseline: 1.1328x; 1.1328x over previous
//
#include <hip/hip_runtime.h>
#include <hip/hip_bf16.h>
#include <math.h>

#define Tn   8192
#define Hn   1024
#define En   8
#define DFFn 4096

typedef __attribute__((ext_vector_type(8))) short bf16x8;  // 8 bf16 = 4 VGPRs
typedef __attribute__((ext_vector_type(4))) float f32x4;

static __device__ inline unsigned short f2bf(float f) {
    __hip_bfloat16 h = __float2bfloat16(f);
    return __builtin_bit_cast(unsigned short, h);
}

// ---------------- fused prep: W1/W2 transpose+cast, gate, x->bf16 ----------
// blocks [0,4096): W1 [1024x4096] -> W1t [4096][1024] bf16
// blocks [4096,8192): W2 [4096x1024] -> W2t [1024][4096] bf16
// blocks [8192,8704): gate scores + top-2 softmax sum + x cast (512 blocks)
__global__ __launch_bounds__(256) void prep(
    const float* __restrict__ W1, const float* __restrict__ W2,
    __hip_bfloat16* __restrict__ W1t, __hip_bfloat16* __restrict__ W2t,
    const float* __restrict__ x, const float* __restrict__ gW,
    const float* __restrict__ gb, unsigned short* __restrict__ xbf,
    float* __restrict__ tokw, float* __restrict__ load_sum,
    int* __restrict__ counts)
{
    const int tid = threadIdx.x;
    int id = blockIdx.x;

    if (id < 8192) {  // ---- transpose+cast ----
        __shared__ float tile[32][33];
        const float* src; __hip_bfloat16* dst; int Kd, Nd, bx, by;
        if (id < 4096) { src = W1; dst = W1t; Kd = Hn;   Nd = DFFn;
                         bx = id & 127; by = id >> 7; }
        else { id -= 4096; src = W2; dst = W2t; Kd = DFFn; Nd = Hn;
               bx = id & 31;  by = id >> 5; }
        const int n0 = bx * 32, k0 = by * 32;
        const int tx = tid & 31, ty = tid >> 5;  // ty: 0..7
        #pragma unroll
        for (int r = 0; r < 32; r += 8)
            tile[ty + r][tx] = src[(size_t)(k0 + ty + r) * Nd + n0 + tx];
        __syncthreads();
        #pragma unroll
        for (int r = 0; r < 32; r += 8)
            dst[(size_t)(n0 + ty + r) * Kd + k0 + tx] =
                __float2bfloat16(tile[tx][ty + r]);
        return;
    }

    // ---- gate + x cast ----
    __shared__ float s_load[En];
    __shared__ int   s_cnt[En];
    if (tid < En) { s_load[tid] = 0.f; s_cnt[tid] = 0; }
    __syncthreads();

    const int bid  = id - 8192;       // 0..511
    const int lane = tid & 63;
    const int wv   = tid >> 6;

    for (int tok = bid * 4 + wv; tok < Tn; tok += 2048) {
        const float4* xr = (const float4*)(x + (size_t)tok * Hn);
        float acc[8] = {0.f,0.f,0.f,0.f,0.f,0.f,0.f,0.f};
        #pragma unroll
        for (int j = 0; j < Hn / 256; ++j) {           // 4 iterations
            int h4 = j * 64 + lane;
            float4 xv = xr[h4];
            ushort4 pk;
            pk.x = f2bf(xv.x); pk.y = f2bf(xv.y);
            pk.z = f2bf(xv.z); pk.w = f2bf(xv.w);
            ((ushort4*)xbf)[(size_t)tok * (Hn / 4) + h4] = pk;
            const float* wr = gW + (size_t)h4 * 4 * En;   // 4 rows of gW
            float xs[4] = {xv.x, xv.y, xv.z, xv.w};
            #pragma unroll
            for (int c = 0; c < 4; ++c)
                #pragma unroll
                for (int e = 0; e < 8; ++e)
                    acc[e] += xs[c] * wr[c * 8 + e];
        }
        #pragma unroll
        for (int e = 0; e < 8; ++e) {
            float v = acc[e];
            #pragma unroll
            for (int off = 32; off > 0; off >>= 1) v += __shfl_xor(v, off, 64);
            acc[e] = v + gb[e];
        }
        if (lane == 0) {
            #pragma unroll
            for (int e = 0; e < 8; ++e) atomicAdd(&s_load[e], acc[e]);
            int i1 = 0; float v1 = acc[0];
            #pragma unroll
            for (int e = 1; e < 8; ++e) if (acc[e] > v1) { v1 = acc[e]; i1 = e; }
            int i2 = -1; float v2 = -3.0e38f;
            #pragma unroll
            for (int e = 0; e < 8; ++e) if (e != i1 && acc[e] > v2) { v2 = acc[e]; i2 = e; }
            atomicAdd(&s_cnt[i1], 1);
            atomicAdd(&s_cnt[i2], 1);
            float e2 = __expf(v2 - v1);
            float t  = 1.0f + e2;
            tokw[tok] = 1.0f / t + e2 / t;   // softmax(top2).sum()
        }
    }
    __syncthreads();
    if (tid < En) {
        atomicAdd(&load_sum[tid], s_load[tid]);
        atomicAdd(&counts[tid],   s_cnt[tid]);
    }
}

// ---------------- m97-style bf16 GEMM, C = epilogue(A @ Bt^T + bias) ------
// A : [M][K] bf16 row-major ; Bt : [N][K] bf16 row-major.
// 1D grid, XCD-aware swizzle (id%8 = xcd, x fastest within an XCD).
// LDS k-chunk rotation (conflict-free fragment reads, verified R4).
// EPI==0: C = bf16( gelu_tanh(v + bias) )   (hdd); last block also writes
//         aux_loss + counts into out_tail (prep's atomics visible across
//         the kernel boundary -- no fence needed).
// EPI==1: C = fp32( (v + bias) * tokw[row] ) (final output)
template<int EPI>
__global__ __launch_bounds__(256) void gemm_bt(
    const __hip_bfloat16* __restrict__ A,
    const __hip_bfloat16* __restrict__ Bt,
    const float* __restrict__ bias,
    const float* __restrict__ tokw,
    void* __restrict__ C, int N, int K, int nxlog2,
    const float* __restrict__ load_sum, const int* __restrict__ counts,
    float* __restrict__ out_tail)
{
    __shared__ __hip_bfloat16 sA[128 * 32];   // no padding: global_load_lds layout
    __shared__ __hip_bfloat16 sB[128 * 32];

    const int tid  = threadIdx.x;
    const int lane = tid & 63;
    const int wv   = tid >> 6;
    const int wm   = (wv >> 1) * 64;
    const int wn   = (wv & 1) * 64;

    // XCD swizzle
    const int id     = blockIdx.x;
    const int xcd    = id & 7;
    const int slot   = id >> 3;
    const int bx     = slot & ((1 << nxlog2) - 1);
    const int ylocal = slot >> nxlog2;
    const int y_per  = (int)((gridDim.x >> 3) >> nxlog2);   // ny/8
    const int by     = xcd * y_per + ylocal;

    const int m0 = by * 128, n0 = bx * 128;

    f32x4 acc[4][4];
    const f32x4 zero = {0.f, 0.f, 0.f, 0.f};
    #pragma unroll
    for (int i = 0; i < 4; ++i)
        #pragma unroll
        for (int j = 0; j < 4; ++j) acc[i][j] = zero;

    // staging: thread t = (row r0 = t>>2, slot s = t&3) fetches global chunk
    // (s - (r0>>1))&3 of that row -> LDS addr t*16B (lane-contiguous).
    const int r0 = tid >> 2;
    const int kc = (((tid & 3) - (r0 >> 1)) & 3) * 8;
    const __hip_bfloat16* gA = A  + (size_t)(m0 + r0) * K + kc;
    const __hip_bfloat16* gB = Bt + (size_t)(n0 + r0) * K + kc;
    const size_t half = (size_t)64 * K;

    const int fr = lane & 15;
    const int fs = (((lane >> 4) + (fr >> 1)) & 3) * 8;   // rotated LDS slot

    for (int k0 = 0; k0 < K; k0 += 32) {
        __syncthreads();
        __builtin_amdgcn_global_load_lds(
            (const __attribute__((address_space(1))) void*)(gA + k0),
            (__attribute__((address_space(3))) void*)(sA + tid * 8), 16, 0, 0);
        __builtin_amdgcn_global_load_lds(
            (const __attribute__((address_space(1))) void*)(gA + half + k0),
            (__attribute__((address_space(3))) void*)(sA + 2048 + tid * 8), 16, 0, 0);
        __builtin_amdgcn_global_load_lds(
            (const __attribute__((address_space(1))) void*)(gB + k0),
            (__attribute__((address_space(3))) void*)(sB + tid * 8), 16, 0, 0);
        __builtin_amdgcn_global_load_lds(
            (const __attribute__((address_space(1))) void*)(gB + half + k0),
            (__attribute__((address_space(3))) void*)(sB + 2048 + tid * 8), 16, 0, 0);
        __syncthreads();

        bf16x8 af[4], bfr[4];
        #pragma unroll
        for (int mi = 0; mi < 4; ++mi)
            af[mi] = *(const bf16x8*)(sA + (wm + mi * 16 + fr) * 32 + fs);
        #pragma unroll
        for (int ni = 0; ni < 4; ++ni)
            bfr[ni] = *(const bf16x8*)(sB + (wn + ni * 16 + fr) * 32 + fs);
        #pragma unroll
        for (int mi = 0; mi < 4; ++mi)
            #pragma unroll
            for (int ni = 0; ni < 4; ++ni)
                acc[mi][ni] = __builtin_amdgcn_mfma_f32_16x16x32_bf16(
                    af[mi], bfr[ni], acc[mi][ni], 0, 0, 0);
    }

    // epilogue: C/D layout col = lane&15, row = (lane>>4)*4 + reg
    #pragma unroll
    for (int mi = 0; mi < 4; ++mi) {
        #pragma unroll
        for (int ni = 0; ni < 4; ++ni) {
            const int col   = n0 + wn + ni * 16 + (lane & 15);
            const int rbase = m0 + wm + mi * 16 + (lane >> 4) * 4;
            const float bv  = bias[col];
            #pragma unroll
            for (int i = 0; i < 4; ++i) {
                const int row = rbase + i;
                float v = acc[mi][ni][i] + bv;
                if (EPI == 0) {
                    // gelu tanh-form: v * sigmoid(2u), exp+rcp only (no div)
                    float vv = v * v;
                    float z  = v * __fmaf_rn(vv, -0.07135607f, -1.59576912f);
                    float e  = __expf(z);            // e^{-2u}
                    float g  = v * __builtin_amdgcn_rcpf(1.0f + e);
                    ((__hip_bfloat16*)C)[(size_t)row * N + col] = __float2bfloat16(g);
                } else {
                    ((float*)C)[(size_t)row * N + col] = v * tokw[row];
                }
            }
        }
    }

    if (EPI == 0 && id == (int)gridDim.x - 1 && tid == 0) {
        float aux = 0.f;
        #pragma unroll
        for (int e = 0; e < En; ++e) {
            float m = load_sum[e] * (1.0f / (float)Tn);
            aux += m * m;
        }
        out_tail[0] = aux;
        #pragma unroll
        for (int e = 0; e < En; ++e) out_tail[1 + e] = (float)counts[e];
    }
}

extern "C" void kernel_launch(void* const* d_in, const int* in_sizes, int n_in,
                              void* d_out, int out_size, void* d_ws, size_t ws_size,
                              hipStream_t stream)
{
    const float* x  = (const float*)d_in[0];
    const float* gW = (const float*)d_in[1];
    const float* gb = (const float*)d_in[2];
    const float* W1 = (const float*)d_in[3];
    const float* b1 = (const float*)d_in[4];
    const float* W2 = (const float*)d_in[5];
    const float* b2 = (const float*)d_in[6];
    float* out = (float*)d_out;

    char* ws = (char*)d_ws;
    __hip_bfloat16* xbf = (__hip_bfloat16*)ws;  ws += (size_t)Tn * Hn * 2;     // 16 MB
    __hip_bfloat16* W1t = (__hip_bfloat16*)ws;  ws += (size_t)Hn * DFFn * 2;   //  8 MB
    __hip_bfloat16* W2t = (__hip_bfloat16*)ws;  ws += (size_t)Hn * DFFn * 2;   //  8 MB
    __hip_bfloat16* hdd = (__hip_bfloat16*)ws;  ws += (size_t)Tn * DFFn * 2;   // 64 MB
    float* tokw     = (float*)ws;               ws += (size_t)Tn * 4;          // 32 KB
    float* load_sum = (float*)ws;               ws += En * 4;
    int*   counts   = (int*)ws;                 ws += En * 4;

    hipMemsetAsync(load_sum, 0, En * 4 * 2, stream);   // load_sum + counts

    prep<<<8704, 256, 0, stream>>>(W1, W2, W1t, W2t, x, gW, gb,
                                   (unsigned short*)xbf, tokw, load_sum, counts);

    // hdd = gelu(x @ W1 + b1)            [8192 x 4096]; nx=32 -> nxlog2=5
    gemm_bt<0><<<(DFFn / 128) * (Tn / 128), 256, 0, stream>>>(
        xbf, W1t, b1, nullptr, hdd, DFFn, Hn, 5,
        load_sum, counts, out + (size_t)Tn * Hn);
    // out = (hdd @ W2 + b2) * tokw[row]  [8192 x 1024]; nx=8 -> nxlog2=3
    gemm_bt<1><<<(Hn / 128) * (Tn / 128), 256, 0, stream>>>(
        hdd, W2t, b2, tokw, out, Hn, DFFn, 3,
        nullptr, nullptr, nullptr);
}

// Round 6
// 323.224 us; speedup vs baseline: 1.1363x; 1.0031x over previous
//
#include <hip/hip_runtime.h>
#include <hip/hip_bf16.h>
#include <math.h>

#define Tn   8192
#define Hn   1024
#define En   8
#define DFFn 4096

typedef __attribute__((ext_vector_type(8))) short bf16x8;  // 8 bf16 = 4 VGPRs
typedef __attribute__((ext_vector_type(4))) float f32x4;

static __device__ inline unsigned short f2bf(float f) {
    __hip_bfloat16 h = __float2bfloat16(f);
    return __builtin_bit_cast(unsigned short, h);
}

// ---------------- prep: W1 transpose+cast, gate, x->bf16 ----------
// blocks [0,4096): W1 [1024x4096] -> W1t [4096][1024] bf16 (32x32 tiles)
// blocks [4096,4608): gate scores + top-2 softmax sum + x cast
__global__ __launch_bounds__(256) void prep(
    const float* __restrict__ W1, unsigned short* __restrict__ W1t,
    const float* __restrict__ x, const float* __restrict__ gW,
    const float* __restrict__ gb, unsigned short* __restrict__ xbf,
    float* __restrict__ tokw, float* __restrict__ load_sum,
    int* __restrict__ counts)
{
    __shared__ float smem[8 * 1024 + En];   // gwt[8][1024] | s_load tail
    __shared__ int   s_cnt[En];
    const int tid = threadIdx.x;
    const int id  = blockIdx.x;

    if (id < 4096) {  // ---- W1 transpose+cast, float4 in / ushort4 out ----
        float* tile = smem;                         // [32][33]
        const int bx = id & 127, by = id >> 7;      // n-tile, k-tile
        const int n0 = bx * 32, k0 = by * 32;
        const int r  = tid >> 3, c4 = (tid & 7) * 4;
        float4 v = *(const float4*)(W1 + (size_t)(k0 + r) * DFFn + n0 + c4);
        tile[(c4 + 0) * 33 + r] = v.x;
        tile[(c4 + 1) * 33 + r] = v.y;
        tile[(c4 + 2) * 33 + r] = v.z;
        tile[(c4 + 3) * 33 + r] = v.w;
        __syncthreads();
        ushort4 pk;
        pk.x = f2bf(tile[r * 33 + c4 + 0]);
        pk.y = f2bf(tile[r * 33 + c4 + 1]);
        pk.z = f2bf(tile[r * 33 + c4 + 2]);
        pk.w = f2bf(tile[r * 33 + c4 + 3]);
        *(ushort4*)(W1t + (size_t)(n0 + r) * Hn + k0 + c4) = pk;
        return;
    }

    // ---- gate + x cast; gW staged into LDS transposed [E][H] ----
    float* gwt    = smem;                // 32 KB
    float* s_load = smem + 8 * 1024;
    if (tid < En) { s_load[tid] = 0.f; s_cnt[tid] = 0; }
    #pragma unroll
    for (int i = 0; i < 32; ++i) {       // 8192 floats, coalesced read, scatter write
        int f = tid + i * 256;
        gwt[(f & 7) * 1024 + (f >> 3)] = gW[f];
    }
    __syncthreads();

    const int bid  = id - 4096;          // 0..511
    const int lane = tid & 63;
    const int wv   = tid >> 6;

    for (int tok = bid * 4 + wv; tok < Tn; tok += 2048) {
        const float4* xr = (const float4*)(x + (size_t)tok * Hn);
        float acc[8] = {0.f,0.f,0.f,0.f,0.f,0.f,0.f,0.f};
        #pragma unroll
        for (int j = 0; j < Hn / 256; ++j) {           // 4 iterations
            int h4 = j * 64 + lane;
            float4 xv = xr[h4];
            ushort4 pk;
            pk.x = f2bf(xv.x); pk.y = f2bf(xv.y);
            pk.z = f2bf(xv.z); pk.w = f2bf(xv.w);
            ((ushort4*)xbf)[(size_t)tok * (Hn / 4) + h4] = pk;
            #pragma unroll
            for (int e = 0; e < 8; ++e) {              // ds_read_b128, 16B lane stride
                const float4 w = *(const float4*)(gwt + e * 1024 + h4 * 4);
                acc[e] += xv.x * w.x + xv.y * w.y + xv.z * w.z + xv.w * w.w;
            }
        }
        #pragma unroll
        for (int e = 0; e < 8; ++e) {
            float v = acc[e];
            #pragma unroll
            for (int off = 32; off > 0; off >>= 1) v += __shfl_xor(v, off, 64);
            acc[e] = v + gb[e];
        }
        if (lane == 0) {
            #pragma unroll
            for (int e = 0; e < 8; ++e) atomicAdd(&s_load[e], acc[e]);
            int i1 = 0; float v1 = acc[0];
            #pragma unroll
            for (int e = 1; e < 8; ++e) if (acc[e] > v1) { v1 = acc[e]; i1 = e; }
            int i2 = -1; float v2 = -3.0e38f;
            #pragma unroll
            for (int e = 0; e < 8; ++e) if (e != i1 && acc[e] > v2) { v2 = acc[e]; i2 = e; }
            atomicAdd(&s_cnt[i1], 1);
            atomicAdd(&s_cnt[i2], 1);
            float e2 = __expf(v2 - v1);
            float t  = 1.0f + e2;
            tokw[tok] = 1.0f / t + e2 / t;   // softmax(top2).sum()
        }
    }
    __syncthreads();
    if (tid < En) {
        atomicAdd(&load_sum[tid], s_load[tid]);
        atomicAdd(&counts[tid],   s_cnt[tid]);
    }
}

// ---------------- m97-style bf16 GEMM, C = epilogue(A @ Bt^T + bias) ------
// A : [M][K] bf16 row-major ; Bt : [N][K] bf16 row-major.
// 1D grid; first nblk blocks are gemm tiles with XCD-aware swizzle
// (id%8 = xcd, x fastest). LDS k-chunk rotation = conflict-free (verified R4).
// EPI==0: blocks >= nblk transpose W2 -> W2t (runs in G1's tail); block nblk
//         also writes aux_loss+counts (prep's atomics visible across launch).
// EPI==0: C = bf16( gelu_tanh(v + bias) )   (hdd)
// EPI==1: C = fp32( (v + bias) * tokw[row] ) (final output)
template<int EPI>
__global__ __launch_bounds__(256) void gemm_bt(
    const __hip_bfloat16* __restrict__ A,
    const __hip_bfloat16* __restrict__ Bt,
    const float* __restrict__ bias,
    const float* __restrict__ tokw,
    void* __restrict__ C, int N, int K, int nxlog2, int nblk,
    const float* __restrict__ W2, unsigned short* __restrict__ W2t,
    const float* __restrict__ load_sum, const int* __restrict__ counts,
    float* __restrict__ out_tail)
{
    __shared__ __hip_bfloat16 sA[128 * 32];   // no padding: global_load_lds layout
    __shared__ __hip_bfloat16 sB[128 * 32];

    const int tid = threadIdx.x;
    const int id  = blockIdx.x;

    if (EPI == 0 && id >= nblk) {   // ---- W2 [4096][1024] -> W2t [1024][4096] ----
        const int tb = id - nblk;                    // 0..4095
        float* tile = (float*)sA;                    // [32][33]
        const int bx = tb & 31, by = tb >> 5;
        const int n0 = bx * 32, k0 = by * 32;
        const int r  = tid >> 3, c4 = (tid & 7) * 4;
        float4 v = *(const float4*)(W2 + (size_t)(k0 + r) * Hn + n0 + c4);
        tile[(c4 + 0) * 33 + r] = v.x;
        tile[(c4 + 1) * 33 + r] = v.y;
        tile[(c4 + 2) * 33 + r] = v.z;
        tile[(c4 + 3) * 33 + r] = v.w;
        __syncthreads();
        ushort4 pk;
        pk.x = f2bf(tile[r * 33 + c4 + 0]);
        pk.y = f2bf(tile[r * 33 + c4 + 1]);
        pk.z = f2bf(tile[r * 33 + c4 + 2]);
        pk.w = f2bf(tile[r * 33 + c4 + 3]);
        *(ushort4*)(W2t + (size_t)(n0 + r) * DFFn + k0 + c4) = pk;
        if (tb == 0 && tid == 0) {
            float aux = 0.f;
            #pragma unroll
            for (int e = 0; e < En; ++e) {
                float m = load_sum[e] * (1.0f / (float)Tn);
                aux += m * m;
            }
            out_tail[0] = aux;
            #pragma unroll
            for (int e = 0; e < En; ++e) out_tail[1 + e] = (float)counts[e];
        }
        return;
    }

    const int lane = tid & 63;
    const int wv   = tid >> 6;
    const int wm   = (wv >> 1) * 64;
    const int wn   = (wv & 1) * 64;

    // XCD swizzle over the gemm sub-grid (nblk blocks)
    const int xcd    = id & 7;
    const int slot   = id >> 3;
    const int bx     = slot & ((1 << nxlog2) - 1);
    const int ylocal = slot >> nxlog2;
    const int y_per  = (nblk >> 3) >> nxlog2;
    const int by     = xcd * y_per + ylocal;

    const int m0 = by * 128, n0 = bx * 128;

    f32x4 acc[4][4];
    const f32x4 zero = {0.f, 0.f, 0.f, 0.f};
    #pragma unroll
    for (int i = 0; i < 4; ++i)
        #pragma unroll
        for (int j = 0; j < 4; ++j) acc[i][j] = zero;

    // staging: thread t = (row r0 = t>>2, slot s = t&3) fetches global chunk
    // (s - (r0>>1))&3 of that row -> LDS addr t*16B (lane-contiguous).
    const int r0 = tid >> 2;
    const int kc = (((tid & 3) - (r0 >> 1)) & 3) * 8;
    const __hip_bfloat16* gA = A  + (size_t)(m0 + r0) * K + kc;
    const __hip_bfloat16* gB = Bt + (size_t)(n0 + r0) * K + kc;
    const size_t half = (size_t)64 * K;

    const int fr = lane & 15;
    const int fs = (((lane >> 4) + (fr >> 1)) & 3) * 8;   // rotated LDS slot

    for (int k0 = 0; k0 < K; k0 += 32) {
        __syncthreads();
        __builtin_amdgcn_global_load_lds(
            (const __attribute__((address_space(1))) void*)(gA + k0),
            (__attribute__((address_space(3))) void*)(sA + tid * 8), 16, 0, 0);
        __builtin_amdgcn_global_load_lds(
            (const __attribute__((address_space(1))) void*)(gA + half + k0),
            (__attribute__((address_space(3))) void*)(sA + 2048 + tid * 8), 16, 0, 0);
        __builtin_amdgcn_global_load_lds(
            (const __attribute__((address_space(1))) void*)(gB + k0),
            (__attribute__((address_space(3))) void*)(sB + tid * 8), 16, 0, 0);
        __builtin_amdgcn_global_load_lds(
            (const __attribute__((address_space(1))) void*)(gB + half + k0),
            (__attribute__((address_space(3))) void*)(sB + 2048 + tid * 8), 16, 0, 0);
        __syncthreads();

        bf16x8 af[4], bfr[4];
        #pragma unroll
        for (int mi = 0; mi < 4; ++mi)
            af[mi] = *(const bf16x8*)(sA + (wm + mi * 16 + fr) * 32 + fs);
        #pragma unroll
        for (int ni = 0; ni < 4; ++ni)
            bfr[ni] = *(const bf16x8*)(sB + (wn + ni * 16 + fr) * 32 + fs);
        #pragma unroll
        for (int mi = 0; mi < 4; ++mi)
            #pragma unroll
            for (int ni = 0; ni < 4; ++ni)
                acc[mi][ni] = __builtin_amdgcn_mfma_f32_16x16x32_bf16(
                    af[mi], bfr[ni], acc[mi][ni], 0, 0, 0);
    }

    // epilogue: C/D layout col = lane&15, row = (lane>>4)*4 + reg
    #pragma unroll
    for (int mi = 0; mi < 4; ++mi) {
        #pragma unroll
        for (int ni = 0; ni < 4; ++ni) {
            const int col   = n0 + wn + ni * 16 + (lane & 15);
            const int rbase = m0 + wm + mi * 16 + (lane >> 4) * 4;
            const float bv  = bias[col];
            #pragma unroll
            for (int i = 0; i < 4; ++i) {
                const int row = rbase + i;
                float v = acc[mi][ni][i] + bv;
                if (EPI == 0) {
                    // gelu tanh-form: v * sigmoid(2u), exp+rcp only (no div)
                    float vv = v * v;
                    float z  = v * __fmaf_rn(vv, -0.07135607f, -1.59576912f);
                    float e  = __expf(z);            // e^{-2u}
                    float g  = v * __builtin_amdgcn_rcpf(1.0f + e);
                    ((__hip_bfloat16*)C)[(size_t)row * N + col] = __float2bfloat16(g);
                } else {
                    ((float*)C)[(size_t)row * N + col] = v * tokw[row];
                }
            }
        }
    }
}

extern "C" void kernel_launch(void* const* d_in, const int* in_sizes, int n_in,
                              void* d_out, int out_size, void* d_ws, size_t ws_size,
                              hipStream_t stream)
{
    const float* x  = (const float*)d_in[0];
    const float* gW = (const float*)d_in[1];
    const float* gb = (const float*)d_in[2];
    const float* W1 = (const float*)d_in[3];
    const float* b1 = (const float*)d_in[4];
    const float* W2 = (const float*)d_in[5];
    const float* b2 = (const float*)d_in[6];
    float* out = (float*)d_out;

    char* ws = (char*)d_ws;
    __hip_bfloat16* xbf = (__hip_bfloat16*)ws;  ws += (size_t)Tn * Hn * 2;     // 16 MB
    __hip_bfloat16* W1t = (__hip_bfloat16*)ws;  ws += (size_t)Hn * DFFn * 2;   //  8 MB
    __hip_bfloat16* W2t = (__hip_bfloat16*)ws;  ws += (size_t)Hn * DFFn * 2;   //  8 MB
    __hip_bfloat16* hdd = (__hip_bfloat16*)ws;  ws += (size_t)Tn * DFFn * 2;   // 64 MB
    float* tokw     = (float*)ws;               ws += (size_t)Tn * 4;          // 32 KB
    float* load_sum = (float*)ws;               ws += En * 4;
    int*   counts   = (int*)ws;                 ws += En * 4;

    hipMemsetAsync(load_sum, 0, En * 4 * 2, stream);   // load_sum + counts

    prep<<<4608, 256, 0, stream>>>(W1, (unsigned short*)W1t, x, gW, gb,
                                   (unsigned short*)xbf, tokw, load_sum, counts);

    // hdd = gelu(x @ W1 + b1) [8192x4096]; 2048 gemm blocks (nx=32) + 4096
    // W2-transpose blocks riding the tail
    gemm_bt<0><<<2048 + 4096, 256, 0, stream>>>(
        xbf, W1t, b1, nullptr, hdd, DFFn, Hn, 5, 2048,
        W2, (unsigned short*)W2t, load_sum, counts, out + (size_t)Tn * Hn);
    // out = (hdd @ W2 + b2) * tokw[row]  [8192 x 1024]; nx=8 -> nxlog2=3
    gemm_bt<1><<<512, 256, 0, stream>>>(
        hdd, W2t, b2, tokw, out, Hn, DFFn, 3, 512,
        nullptr, nullptr, nullptr, nullptr, nullptr);
}

// Round 7
// 314.311 us; speedup vs baseline: 1.1685x; 1.0284x over previous
//
#include <hip/hip_runtime.h>
#include <hip/hip_bf16.h>
#include <math.h>

#define Tn   8192
#define Hn   1024
#define En   8
#define DFFn 4096

typedef __attribute__((ext_vector_type(8))) short bf16x8;  // 8 bf16 = 4 VGPRs
typedef __attribute__((ext_vector_type(4))) float f32x4;

static __device__ inline unsigned short f2bf(float f) {
    __hip_bfloat16 h = __float2bfloat16(f);
    return __builtin_bit_cast(unsigned short, h);
}

// ---------------- prep: gate first (overlaps), then W1 transpose ----------
// blocks [0,1024): gate scores + top-2 softmax sum + x->bf16 cast
// blocks [1024,5120): W1 [1024x4096] -> W1t [4096][1024] bf16 (32x32 tiles)
__global__ __launch_bounds__(256) void prep(
    const float* __restrict__ W1, unsigned short* __restrict__ W1t,
    const float* __restrict__ x, const float* __restrict__ gW,
    const float* __restrict__ gb, unsigned short* __restrict__ xbf,
    float* __restrict__ tokw, float* __restrict__ load_sum,
    int* __restrict__ counts)
{
    __shared__ float smem[8 * 1024 + En];   // gwt[8][1024] | s_load tail
    __shared__ int   s_cnt[En];
    const int tid = threadIdx.x;
    const int id  = blockIdx.x;

    if (id >= 1024) {  // ---- W1 transpose+cast, float4 in / ushort4 out ----
        const int tb = id - 1024;
        float* tile = smem;                         // [32][33]
        const int bx = tb & 127, by = tb >> 7;      // n-tile, k-tile
        const int n0 = bx * 32, k0 = by * 32;
        const int r  = tid >> 3, c4 = (tid & 7) * 4;
        float4 v = *(const float4*)(W1 + (size_t)(k0 + r) * DFFn + n0 + c4);
        tile[(c4 + 0) * 33 + r] = v.x;
        tile[(c4 + 1) * 33 + r] = v.y;
        tile[(c4 + 2) * 33 + r] = v.z;
        tile[(c4 + 3) * 33 + r] = v.w;
        __syncthreads();
        ushort4 pk;
        pk.x = f2bf(tile[r * 33 + c4 + 0]);
        pk.y = f2bf(tile[r * 33 + c4 + 1]);
        pk.z = f2bf(tile[r * 33 + c4 + 2]);
        pk.w = f2bf(tile[r * 33 + c4 + 3]);
        *(ushort4*)(W1t + (size_t)(n0 + r) * Hn + k0 + c4) = pk;
        return;
    }

    // ---- gate + x cast; gW staged into LDS transposed [E][H] ----
    float* gwt    = smem;                // 32 KB
    float* s_load = smem + 8 * 1024;
    if (tid < En) { s_load[tid] = 0.f; s_cnt[tid] = 0; }
    #pragma unroll
    for (int i = 0; i < 32; ++i) {       // 8192 floats, coalesced read
        int f = tid + i * 256;
        gwt[(f & 7) * 1024 + (f >> 3)] = gW[f];
    }
    __syncthreads();

    const int lane = tid & 63;
    const int wv   = tid >> 6;

    for (int tok = id * 4 + wv; tok < Tn; tok += 4096) {   // 2 toks/wave
        const float4* xr = (const float4*)(x + (size_t)tok * Hn);
        float acc[8] = {0.f,0.f,0.f,0.f,0.f,0.f,0.f,0.f};
        #pragma unroll
        for (int j = 0; j < Hn / 256; ++j) {           // 4 iterations
            int h4 = j * 64 + lane;
            float4 xv = xr[h4];
            ushort4 pk;
            pk.x = f2bf(xv.x); pk.y = f2bf(xv.y);
            pk.z = f2bf(xv.z); pk.w = f2bf(xv.w);
            ((ushort4*)xbf)[(size_t)tok * (Hn / 4) + h4] = pk;
            #pragma unroll
            for (int e = 0; e < 8; ++e) {              // ds_read_b128, 16B stride
                const float4 w = *(const float4*)(gwt + e * 1024 + h4 * 4);
                acc[e] += xv.x * w.x + xv.y * w.y + xv.z * w.z + xv.w * w.w;
            }
        }
        #pragma unroll
        for (int e = 0; e < 8; ++e) {
            float v = acc[e];
            #pragma unroll
            for (int off = 32; off > 0; off >>= 1) v += __shfl_xor(v, off, 64);
            acc[e] = v + gb[e];
        }
        if (lane == 0) {
            #pragma unroll
            for (int e = 0; e < 8; ++e) atomicAdd(&s_load[e], acc[e]);
            int i1 = 0; float v1 = acc[0];
            #pragma unroll
            for (int e = 1; e < 8; ++e) if (acc[e] > v1) { v1 = acc[e]; i1 = e; }
            int i2 = -1; float v2 = -3.0e38f;
            #pragma unroll
            for (int e = 0; e < 8; ++e) if (e != i1 && acc[e] > v2) { v2 = acc[e]; i2 = e; }
            atomicAdd(&s_cnt[i1], 1);
            atomicAdd(&s_cnt[i2], 1);
            float e2 = __expf(v2 - v1);
            float t  = 1.0f + e2;
            tokw[tok] = 1.0f / t + e2 / t;   // softmax(top2).sum()
        }
    }
    __syncthreads();
    if (tid < En) {
        atomicAdd(&load_sum[tid], s_load[tid]);
        atomicAdd(&counts[tid],   s_cnt[tid]);
    }
}

// ---------------- BK=64 bf16 GEMM, C = epilogue(A @ Bt^T + bias) ----------
// A : [M][K] bf16 row-major ; Bt : [N][K] bf16 row-major.
// One barrier-pair per K=64 (vs 32): halves the vmcnt(0) drain count.
// LDS layout: row r holds 8 slots of 8 bf16; global k-chunk c of row r lives
// at slot (c + (r>>1))&7  ->  fragment-read bank-group = slot, 2 lanes/group
// (conflict-free); staging stays wave-uniform-base + lane*16B.
// EPI==0: blocks >= nblk transpose W2 -> W2t + block nblk writes aux/counts.
// EPI==0: C = bf16( gelu_tanh(v + bias) )   (hdd)
// EPI==1: C = fp32( (v + bias) * tokw[row] ) (final output)
template<int EPI>
__global__ __launch_bounds__(256) void gemm_bt(
    const __hip_bfloat16* __restrict__ A,
    const __hip_bfloat16* __restrict__ Bt,
    const float* __restrict__ bias,
    const float* __restrict__ tokw,
    void* __restrict__ C, int N, int K, int nxlog2, int nblk,
    const float* __restrict__ W2, unsigned short* __restrict__ W2t,
    const float* __restrict__ load_sum, const int* __restrict__ counts,
    float* __restrict__ out_tail)
{
    __shared__ __hip_bfloat16 sA[128 * 64];   // 16 KB
    __shared__ __hip_bfloat16 sB[128 * 64];   // 16 KB

    const int tid = threadIdx.x;
    const int id  = blockIdx.x;

    if (EPI == 0 && id >= nblk) {   // ---- W2 [4096][1024] -> W2t [1024][4096] ----
        const int tb = id - nblk;                    // 0..4095
        float* tile = (float*)sA;                    // [32][33]
        const int bx = tb & 31, by = tb >> 5;
        const int n0 = bx * 32, k0 = by * 32;
        const int r  = tid >> 3, c4 = (tid & 7) * 4;
        float4 v = *(const float4*)(W2 + (size_t)(k0 + r) * Hn + n0 + c4);
        tile[(c4 + 0) * 33 + r] = v.x;
        tile[(c4 + 1) * 33 + r] = v.y;
        tile[(c4 + 2) * 33 + r] = v.z;
        tile[(c4 + 3) * 33 + r] = v.w;
        __syncthreads();
        ushort4 pk;
        pk.x = f2bf(tile[r * 33 + c4 + 0]);
        pk.y = f2bf(tile[r * 33 + c4 + 1]);
        pk.z = f2bf(tile[r * 33 + c4 + 2]);
        pk.w = f2bf(tile[r * 33 + c4 + 3]);
        *(ushort4*)(W2t + (size_t)(n0 + r) * DFFn + k0 + c4) = pk;
        if (tb == 0 && tid == 0) {
            float aux = 0.f;
            #pragma unroll
            for (int e = 0; e < En; ++e) {
                float m = load_sum[e] * (1.0f / (float)Tn);
                aux += m * m;
            }
            out_tail[0] = aux;
            #pragma unroll
            for (int e = 0; e < En; ++e) out_tail[1 + e] = (float)counts[e];
        }
        return;
    }

    const int lane = tid & 63;
    const int wv   = tid >> 6;
    const int wm   = (wv >> 1) * 64;
    const int wn   = (wv & 1) * 64;

    // XCD swizzle over the gemm sub-grid (nblk blocks)
    const int xcd    = id & 7;
    const int slot_  = id >> 3;
    const int bx     = slot_ & ((1 << nxlog2) - 1);
    const int ylocal = slot_ >> nxlog2;
    const int y_per  = (nblk >> 3) >> nxlog2;
    const int by     = xcd * y_per + ylocal;

    const int m0 = by * 128, n0 = bx * 128;

    f32x4 acc[4][4];
    const f32x4 zero = {0.f, 0.f, 0.f, 0.f};
    #pragma unroll
    for (int i = 0; i < 4; ++i)
        #pragma unroll
        for (int j = 0; j < 4; ++j) acc[i][j] = zero;

    // staging map: instr j of wave wq covers rows wq*32+j*8 .. +7 (8 slots each)
    const int wq   = tid >> 6;
    const int slot = tid & 7;
    const __hip_bfloat16* gAj[4];
    const __hip_bfloat16* gBj[4];
    int loff[4];
    #pragma unroll
    for (int j = 0; j < 4; ++j) {
        const int row = wq * 32 + j * 8 + ((tid & 63) >> 3);
        const int c   = (slot - (row >> 1)) & 7;          // global k-chunk
        gAj[j]  = A  + (size_t)(m0 + row) * K + c * 8;
        gBj[j]  = Bt + (size_t)(n0 + row) * K + c * 8;
        loff[j] = row * 64 + slot * 8;                    // == uniform + lane*8
    }

    const int fr = lane & 15;
    const int fq = lane >> 4;         // k-group 0..3 within a K=32 step

    for (int k0 = 0; k0 < K; k0 += 64) {
        __syncthreads();
        #pragma unroll
        for (int j = 0; j < 4; ++j) {
            __builtin_amdgcn_global_load_lds(
                (const __attribute__((address_space(1))) void*)(gAj[j] + k0),
                (__attribute__((address_space(3))) void*)(sA + loff[j]), 16, 0, 0);
            __builtin_amdgcn_global_load_lds(
                (const __attribute__((address_space(1))) void*)(gBj[j] + k0),
                (__attribute__((address_space(3))) void*)(sB + loff[j]), 16, 0, 0);
        }
        __syncthreads();

        #pragma unroll
        for (int ks = 0; ks < 2; ++ks) {
            bf16x8 af[4], bfr[4];
            #pragma unroll
            for (int mi = 0; mi < 4; ++mi) {
                const int r = wm + mi * 16 + fr;
                const int s = (ks * 4 + fq + ((r >> 1) & 7)) & 7;
                af[mi] = *(const bf16x8*)(sA + r * 64 + s * 8);
            }
            #pragma unroll
            for (int ni = 0; ni < 4; ++ni) {
                const int r = wn + ni * 16 + fr;
                const int s = (ks * 4 + fq + ((r >> 1) & 7)) & 7;
                bfr[ni] = *(const bf16x8*)(sB + r * 64 + s * 8);
            }
            #pragma unroll
            for (int mi = 0; mi < 4; ++mi)
                #pragma unroll
                for (int ni = 0; ni < 4; ++ni)
                    acc[mi][ni] = __builtin_amdgcn_mfma_f32_16x16x32_bf16(
                        af[mi], bfr[ni], acc[mi][ni], 0, 0, 0);
        }
    }

    // epilogue: C/D layout col = lane&15, row = (lane>>4)*4 + reg
    #pragma unroll
    for (int mi = 0; mi < 4; ++mi) {
        #pragma unroll
        for (int ni = 0; ni < 4; ++ni) {
            const int col   = n0 + wn + ni * 16 + (lane & 15);
            const int rbase = m0 + wm + mi * 16 + (lane >> 4) * 4;
            const float bv  = bias[col];
            #pragma unroll
            for (int i = 0; i < 4; ++i) {
                const int row = rbase + i;
                float v = acc[mi][ni][i] + bv;
                if (EPI == 0) {
                    // gelu tanh-form: v * sigmoid(2u), exp+rcp only (no div)
                    float vv = v * v;
                    float z  = v * __fmaf_rn(vv, -0.07135607f, -1.59576912f);
                    float e  = __expf(z);            // e^{-2u}
                    float g  = v * __builtin_amdgcn_rcpf(1.0f + e);
                    ((__hip_bfloat16*)C)[(size_t)row * N + col] = __float2bfloat16(g);
                } else {
                    ((float*)C)[(size_t)row * N + col] = v * tokw[row];
                }
            }
        }
    }
}

extern "C" void kernel_launch(void* const* d_in, const int* in_sizes, int n_in,
                              void* d_out, int out_size, void* d_ws, size_t ws_size,
                              hipStream_t stream)
{
    const float* x  = (const float*)d_in[0];
    const float* gW = (const float*)d_in[1];
    const float* gb = (const float*)d_in[2];
    const float* W1 = (const float*)d_in[3];
    const float* b1 = (const float*)d_in[4];
    const float* W2 = (const float*)d_in[5];
    const float* b2 = (const float*)d_in[6];
    float* out = (float*)d_out;

    char* ws = (char*)d_ws;
    __hip_bfloat16* xbf = (__hip_bfloat16*)ws;  ws += (size_t)Tn * Hn * 2;     // 16 MB
    __hip_bfloat16* W1t = (__hip_bfloat16*)ws;  ws += (size_t)Hn * DFFn * 2;   //  8 MB
    __hip_bfloat16* W2t = (__hip_bfloat16*)ws;  ws += (size_t)Hn * DFFn * 2;   //  8 MB
    __hip_bfloat16* hdd = (__hip_bfloat16*)ws;  ws += (size_t)Tn * DFFn * 2;   // 64 MB
    float* tokw     = (float*)ws;               ws += (size_t)Tn * 4;          // 32 KB
    float* load_sum = (float*)ws;               ws += En * 4;
    int*   counts   = (int*)ws;                 ws += En * 4;

    hipMemsetAsync(load_sum, 0, En * 4 * 2, stream);   // load_sum + counts

    prep<<<5120, 256, 0, stream>>>(W1, (unsigned short*)W1t, x, gW, gb,
                                   (unsigned short*)xbf, tokw, load_sum, counts);

    // hdd = gelu(x @ W1 + b1) [8192x4096]; 2048 gemm blocks (nx=32) + 4096
    // W2-transpose blocks riding the tail
    gemm_bt<0><<<2048 + 4096, 256, 0, stream>>>(
        xbf, W1t, b1, nullptr, hdd, DFFn, Hn, 5, 2048,
        W2, (unsigned short*)W2t, load_sum, counts, out + (size_t)Tn * Hn);
    // out = (hdd @ W2 + b2) * tokw[row]  [8192 x 1024]; nx=8 -> nxlog2=3
    gemm_bt<1><<<512, 256, 0, stream>>>(
        hdd, W2t, b2, tokw, out, Hn, DFFn, 3, 512,
        nullptr, nullptr, nullptr, nullptr, nullptr);
}